// Round 5
// baseline (304.166 us; speedup 1.0000x reference)
//
#include <hip/hip_runtime.h>

// CharAttention: per (b,w) causal char-attention; only row x_end_idx[b,w]
// survives the gather -> compute only that row, with q folded through Wk
// and Wv folded through Wproj (per-launch prep kernel):
//   M_h[c'][c] = 0.25 * sum_d Wq[c'][16h+d] * Wk[c][16h+d]     (2x32x32)
//   N_h[c][i]  =        sum_d Wv[c][16h+d]  * Wproj[16h+d][i]  (2x32x32)
//   rk[h][c]   = sum_c' x[qidx][c'] * M_h[c'][c]
//   s[h][j]    = x[j] . rk[h]   (j<=qidx);  e = exp(s) (no max-sub: |s|~N(0,1))
//   y[h][c]    = (sum_j e[h][j] x[j][c]) / sum_j e[h][j]
//   out[i]     = x[qidx][i] + sum_h sum_c y[h][c] * N_h[c][i]
//
// Round-4 lesson: the per-CU LDS pipe (incl. __shfl bpermutes) was the
// bottleneck (~500+ cyc/problem). This version: M,N live in VGPRs
// (64 regs, loaded once/wave), 7 shfls/problem, distinct LDS reads
// split across half-waves. One problem per wave, 4 waves/block.

#define CB      24
#define CC      32
#define DD      16
#define THREEC  96
#define NBW     (512 * 128)
#define WPB     4
#define XSS     34              // xs row stride: even (8B-aligned rows), 2-way banks max

struct __align__(16) WaveSmem {
    float xs[CB][XSS];          // staged x rows (3264 B)
    float rks[2][CC];           // rk per head (256 B)
    float es[CB][2];            // e[j][h] pairs; masked j -> 0 (192 B)
    float ys[CC][2];            // normalized y[c][h] pairs (256 B)
};                              // 3968 B -> 4 waves = 15872 B/block

__device__ __forceinline__ void wave_fence() {
    __asm__ volatile("s_waitcnt lgkmcnt(0)" ::: "memory");
}

// ---- prep: M[2][32][32] then N[2][32][32] into ws (16 KB) ----
__global__ void prep_kernel(const float* __restrict__ w_attn,
                            const float* __restrict__ w_proj,
                            float* __restrict__ ws)
{
    const int t = blockIdx.x * 256 + threadIdx.x;   // 0..4095
    if (t < 2048) {                                  // M[h][c'][c]
        const int h = t >> 10, rem = t & 1023, cp = rem >> 5, c = rem & 31;
        float a = 0.f;
        #pragma unroll
        for (int d = 0; d < DD; ++d)
            a = fmaf(w_attn[cp * THREEC + 16 * h + d],
                     w_attn[c * THREEC + CC + 16 * h + d], a);
        ws[t] = a * 0.25f;                           // fold 1/sqrt(D)
    } else {                                         // N[h][c][i]
        const int u = t - 2048;
        const int h = u >> 10, rem = u & 1023, c = rem >> 5, i = rem & 31;
        float a = 0.f;
        #pragma unroll
        for (int d = 0; d < DD; ++d)
            a = fmaf(w_attn[c * THREEC + 2 * CC + 16 * h + d],
                     w_proj[(16 * h + d) * CC + i], a);
        ws[t] = a;
    }
}

__global__ __launch_bounds__(256, 4) void char_attn_kernel(
    const float* __restrict__ x,        // [B*W, 24, 32]
    const int*   __restrict__ xend,     // [B*W]
    const float* __restrict__ ws,       // M[2][32][32], N[2][32][32]
    float*       __restrict__ out)      // [B*W, 32]
{
    __shared__ WaveSmem sm[WPB];

    const int tid  = threadIdx.x;
    const int lane = tid & 63;
    const int wave = tid >> 6;
    WaveSmem& S = sm[wave];

    const int i32  = lane & 31;
    const int half = lane >> 5;
    const int bid  = blockIdx.x * WPB + wave;   // one problem per wave

    const float* Mw = ws;                        // [2][32][32]
    const float* Nw = ws + 2048;                 // [2][32][32]

    // ---- fused weights in registers (loaded once; L1-resident) ----
    float Mreg[CC];                              // M[half][c'][i32]
    #pragma unroll
    for (int cp = 0; cp < CC; ++cp)
        Mreg[cp] = Mw[(half * CC + cp) * CC + i32];
    float Nreg[2][DD];                           // N[h][half*16+k][i32]
    #pragma unroll
    for (int h = 0; h < 2; ++h)
        #pragma unroll
        for (int k = 0; k < DD; ++k)
            Nreg[h][k] = Nw[(h * CC + half * DD + k) * CC + i32];

    const int qidx = xend[bid];                  // wave-uniform scalar load
    const int L    = qidx + 1;
    const float* xb = x + (size_t)bid * (CB * CC);

    // ---- P0: stage x rows 0..qidx (coalesced float2) ----
    {
        const float2* xb2 = (const float2*)xb;
        const int n2 = L * (CC / 2);             // <= 384
        for (int t = lane; t < n2; t += 64) {
            float2 v = xb2[t];
            const int r = t >> 4, c = (t & 15) * 2;
            *(float2*)&S.xs[r][c] = v;
        }
    }
    wave_fence();

    // ---- P1: rk[half][i32] = sum_c' xs[qidx][c'] * Mreg[c'] ----
    {
        float a0 = 0.f, a1 = 0.f;
        #pragma unroll
        for (int cp = 0; cp < CC; cp += 2) {
            float2 xv = *(const float2*)&S.xs[qidx][cp];   // broadcast
            a0 = fmaf(xv.x, Mreg[cp],     a0);
            a1 = fmaf(xv.y, Mreg[cp + 1], a1);
        }
        S.rks[half][i32] = a0 + a1;
    }
    wave_fence();

    // ---- P2: scores (c split across halves) + exp; es[j] = (e0,e1) ----
    {
        float s0 = 0.f, s1 = 0.f;
        if (i32 <= qidx) {                       // j = i32
            const int cb = half * DD;
            #pragma unroll
            for (int t = 0; t < DD; t += 2) {
                float2 xv = *(const float2*)&S.xs[i32][cb + t];  // 2-way banks
                s0 = fmaf(xv.x, S.rks[0][cb + t],     s0);
                s0 = fmaf(xv.y, S.rks[0][cb + t + 1], s0);
                s1 = fmaf(xv.x, S.rks[1][cb + t],     s1);
                s1 = fmaf(xv.y, S.rks[1][cb + t + 1], s1);
            }
        }
        s0 += __shfl_xor(s0, 32);
        s1 += __shfl_xor(s1, 32);
        // no max-subtraction: s ~ N(0,1), exp safe in fp32
        const float e0 = (i32 <= qidx) ? __expf(s0) : 0.f;
        const float e1 = (i32 <= qidx) ? __expf(s1) : 0.f;
        if (half == 0 && i32 < CB)
            *(float2*)&S.es[i32][0] = make_float2(e0, e1);
    }
    wave_fence();

    // ---- P3: y[h][i32] partial over j-half, + sums; normalize on write ----
    {
        float y0 = 0.f, y1 = 0.f, ps0 = 0.f, ps1 = 0.f;
        #pragma unroll
        for (int jj = 0; jj < 12; ++jj) {
            const int j  = half * 12 + jj;
            const int jr = (j <= qidx) ? j : qidx;     // valid row; e[j]=0 masks
            float2 ev = *(const float2*)&S.es[j][0];   // uniform per half
            float  xv = S.xs[jr][i32];                 // distinct, 2-way banks
            y0 = fmaf(ev.x, xv, y0);  ps0 += ev.x;
            y1 = fmaf(ev.y, xv, y1);  ps1 += ev.y;
        }
        y0  += __shfl_xor(y0, 32);
        y1  += __shfl_xor(y1, 32);
        ps0 += __shfl_xor(ps0, 32);
        ps1 += __shfl_xor(ps1, 32);
        if (half == 0)
            *(float2*)&S.ys[i32][0] = make_float2(y0 / ps0, y1 / ps1);
    }
    wave_fence();

    // ---- P4: out[i32] = xs[qidx][i32] + sum_{h,c} y[h][c] * N_h[c][i32] ----
    {
        float a0 = 0.f, a1 = 0.f;
        #pragma unroll
        for (int k = 0; k < DD; ++k) {
            const int c = half * DD + k;
            float2 yv = *(const float2*)&S.ys[c][0];   // uniform per half
            a0 = fmaf(yv.x, Nreg[0][k], a0);
            a1 = fmaf(yv.y, Nreg[1][k], a1);
        }
        float a = a0 + a1;
        a += __shfl_xor(a, 32);
        if (half == 0)
            out[(size_t)bid * CC + i32] = a + S.xs[qidx][i32];
    }
}

extern "C" void kernel_launch(void* const* d_in, const int* in_sizes, int n_in,
                              void* d_out, int out_size, void* d_ws, size_t ws_size,
                              hipStream_t stream) {
    const float* x      = (const float*)d_in[0];
    const int*   xend   = (const int*)d_in[1];
    const float* w_attn = (const float*)d_in[2];
    const float* w_proj = (const float*)d_in[3];
    float* out = (float*)d_out;
    float* ws  = (float*)d_ws;                   // 16 KB used

    prep_kernel<<<dim3(16), dim3(256), 0, stream>>>(w_attn, w_proj, ws);
    char_attn_kernel<<<dim3(NBW / WPB), dim3(WPB * 64), 0, stream>>>(
        x, xend, ws, out);
}